// Round 2
// baseline (724.044 us; speedup 1.0000x reference)
//
#include <hip/hip_runtime.h>

// Problem constants (shapes fixed by the reference; N/E/EREL derived at launch)
//   H=2 heads, D=32, H*D=64, ED=64, DMID=IN=64, DREL=32

// ---------------------------------------------------------------------------
// Projection + attention-logit kernel.
// One wave (64 lanes) per row. Computes outF[row][c] = X[row,:] @ W[:,c] + b[c]
// and optional per-head reductions sum_d avec[..]*relu(outF) -> outA[row][head].
// mode 0: avec index = lane (attn_src/attn_dst layout [H][D])
// mode 1: avec index = head*64 + d        (attn_edge, mid half)
// mode 2: avec index = head*64 + 32 + d   (attn_edge, rel half)
// ---------------------------------------------------------------------------
__global__ __launch_bounds__(256) void proj_attn_kernel(
    const float* __restrict__ X, const float* __restrict__ W,
    const float* __restrict__ bias, const float* __restrict__ avec0,
    const float* __restrict__ avec1, int mode, int nrows, int K,
    float* __restrict__ outF, float* __restrict__ outA0, float* __restrict__ outA1)
{
    __shared__ float Wsh[64 * 64];
    int t = threadIdx.x;
    for (int i = t; i < K * 64; i += 256) Wsh[i] = W[i];
    __syncthreads();

    int wave = t >> 6, lane = t & 63;
    int head = lane >> 5, d = lane & 31;
    int row = blockIdx.x * 4 + wave;
    if (row >= nrows) return;

    float bc = bias[lane];
    int aidx = (mode == 0) ? lane : (head * 64 + d + ((mode == 2) ? 32 : 0));
    float c0 = avec0 ? avec0[aidx] : 0.f;
    float c1 = avec1 ? avec1[aidx] : 0.f;

    float x = (lane < K) ? X[(size_t)row * K + lane] : 0.f;
    float acc = bc;
#pragma unroll 8
    for (int k = 0; k < K; ++k) {
        float xk = __shfl(x, k, 64);
        acc += xk * Wsh[k * 64 + lane];
    }
    outF[(size_t)row * 64 + lane] = acc;

    float r = fmaxf(acc, 0.f);
    if (outA0) {
        float s = r * c0;
        for (int m = 16; m >= 1; m >>= 1) s += __shfl_xor(s, m, 32);
        if (d == 0) outA0[row * 2 + head] = s;
    }
    if (outA1) {
        float s = r * c1;
        for (int m = 16; m >= 1; m >>= 1) s += __shfl_xor(s, m, 32);
        if (d == 0) outA1[row * 2 + head] = s;
    }
}

// ---------------------------------------------------------------------------
// Per-edge logits e[E][2] + dst degree histogram
// ---------------------------------------------------------------------------
__global__ __launch_bounds__(256) void edge_logits_kernel(
    const int* __restrict__ src_idx, const int* __restrict__ dst_idx,
    const int* __restrict__ hn, const int* __restrict__ he,
    const float2* __restrict__ e_src, const float2* __restrict__ e_dst,
    const float2* __restrict__ em, const float2* __restrict__ er,
    float2* __restrict__ e, int* __restrict__ deg, int E)
{
    int i = blockIdx.x * blockDim.x + threadIdx.x;
    if (i >= E) return;
    int s = src_idx[i], dn = dst_idx[i], hni = hn[i], hei = he[i];
    float2 a = e_src[s], b = e_dst[dn], c = em[hni], d = er[hei];
    float2 r;
    r.x = a.x + b.x + c.x + d.x;
    r.y = a.y + b.y + c.y + d.y;
    e[i] = r;
    atomicAdd(&deg[dn], 1);
}

// ---------------------------------------------------------------------------
// Single-block exclusive scan of deg -> row_ptr[N+1], cursor[N]
// ---------------------------------------------------------------------------
__global__ __launch_bounds__(1024) void scan_kernel(
    const int* __restrict__ deg, int* __restrict__ row_ptr,
    int* __restrict__ cursor, int N)
{
    __shared__ int part[1024];
    int t = threadIdx.x;
    int chunk = (N + 1023) / 1024;
    int lo = t * chunk, hi = min(lo + chunk, N);
    int s = 0;
    for (int i = lo; i < hi; ++i) s += deg[i];
    part[t] = s;
    __syncthreads();
    for (int off = 1; off < 1024; off <<= 1) {
        int v = 0;
        if (t >= off) v = part[t - off];
        __syncthreads();
        if (t >= off) part[t] += v;
        __syncthreads();
    }
    int ex = (t == 0) ? 0 : part[t - 1];
    for (int i = lo; i < hi; ++i) {
        row_ptr[i] = ex;
        cursor[i] = ex;
        ex += deg[i];
    }
    if (t == 1023) row_ptr[N] = part[1023];
}

// ---------------------------------------------------------------------------
// Scatter edge ids into CSR order
// ---------------------------------------------------------------------------
__global__ __launch_bounds__(256) void scatter_kernel(
    const int* __restrict__ dst_idx, int* __restrict__ cursor,
    int* __restrict__ edge_ids, int E)
{
    int i = blockIdx.x * blockDim.x + threadIdx.x;
    if (i >= E) return;
    int pos = atomicAdd(&cursor[dst_idx[i]], 1);
    edge_ids[pos] = i;
}

// ---------------------------------------------------------------------------
// Per-node aggregation: softmax over incoming edges, weighted sums,
// fc_edge (ft2 @ W_edge + b_edge), residual, relu, L2 normalize.
// One wave per node; lane c = head*32 + dj output channel.
// ---------------------------------------------------------------------------
__global__ __launch_bounds__(256) void aggregate_kernel(
    const int* __restrict__ row_ptr, const int* __restrict__ edge_ids,
    const int* __restrict__ src_idx, const int* __restrict__ hn,
    const int* __restrict__ he, const float2* __restrict__ e,
    const float* __restrict__ hp, const float* __restrict__ midf,
    const float* __restrict__ relf, const float* __restrict__ We,
    const float* __restrict__ be, float* __restrict__ out, int N)
{
    __shared__ float WeSh[64 * 32];
    __shared__ float ft2sh[4][128];
    int t = threadIdx.x;
    for (int i = t; i < 64 * 32; i += 256) WeSh[i] = We[i];
    __syncthreads();

    int wave = t >> 6, lane = t & 63;
    int head = lane >> 5, dj = lane & 31;
    int n = blockIdx.x * 4 + wave;
    bool valid = n < N;
    int nn = valid ? n : 0;

    int start = row_ptr[nn], end = row_ptr[nn + 1];

    // pass 1: per-head max over incoming edges (lanes stride the list)
    float m0 = -1e30f, m1 = -1e30f;
    for (int i = start + lane; i < end; i += 64) {
        int eid = edge_ids[i];
        float2 ev = e[eid];
        m0 = fmaxf(m0, ev.x);
        m1 = fmaxf(m1, ev.y);
    }
    for (int m = 32; m >= 1; m >>= 1) {
        m0 = fmaxf(m0, __shfl_xor(m0, m, 64));
        m1 = fmaxf(m1, __shfl_xor(m1, m, 64));
    }

    // pass 2: exp-sum + weighted aggregation (all lanes walk each edge)
    float rstc = 0.f, f0 = 0.f, f1 = 0.f, den0 = 0.f, den1 = 0.f;
    for (int i = start; i < end; ++i) {
        int eid = edge_ids[i];
        int s = src_idx[eid];
        int hni = hn[eid];
        int hei = he[eid];
        float2 ev = e[eid];
        float a0 = __expf(ev.x - m0);
        float a1 = __expf(ev.y - m1);
        den0 += a0;
        den1 += a1;
        float ac = head ? a1 : a0;
        rstc += hp[(size_t)s * 64 + lane] * ac;
        // ft2 lane mapping: f0 = head0 concat-channel `lane`, f1 = head1 channel `lane`
        float g0 = (lane < 32) ? midf[(size_t)hni * 64 + lane]
                               : relf[(size_t)hei * 64 + (lane - 32)];
        float g1 = (lane < 32) ? midf[(size_t)hni * 64 + 32 + lane]
                               : relf[(size_t)hei * 64 + 32 + (lane - 32)];
        f0 += g0 * a0;
        f1 += g1 * a1;
    }
    float inv0 = den0 > 0.f ? 1.f / den0 : 0.f;
    float inv1 = den1 > 0.f ? 1.f / den1 : 0.f;
    rstc *= head ? inv1 : inv0;

    ft2sh[wave][lane] = f0 * inv0;
    ft2sh[wave][64 + lane] = f1 * inv1;
    __syncthreads();

    // fc_edge: out[h][dj] = sum_dd ft2[h][dd] * We[dd][dj]  (+ b_edge[dj])
    float fc = be[dj];
#pragma unroll 8
    for (int dd = 0; dd < 64; ++dd)
        fc += ft2sh[wave][head * 64 + dd] * WeSh[dd * 32 + dj];

    float val = rstc + fc + hp[(size_t)nn * 64 + lane];
    val = fmaxf(val, 0.f);

    // L2 norm across the wave's 64 channels
    float ss = val * val;
    for (int m = 32; m >= 1; m >>= 1) ss += __shfl_xor(ss, m, 64);
    float nrm = sqrtf(ss);
    float invn = 1.f / fmaxf(nrm, 1e-12f);
    if (valid) out[(size_t)nn * 64 + lane] = val * invn;
}

// ---------------------------------------------------------------------------
extern "C" void kernel_launch(void* const* d_in, const int* in_sizes, int n_in,
                              void* d_out, int out_size, void* d_ws, size_t ws_size,
                              hipStream_t stream)
{
    const float* h         = (const float*)d_in[0];
    const float* W_t       = (const float*)d_in[1];
    const float* b_t       = (const float*)d_in[2];
    const float* nfeat_mid = (const float*)d_in[3];
    const float* W_mid     = (const float*)d_in[4];
    const float* b_mid     = (const float*)d_in[5];
    const float* efeat_rel = (const float*)d_in[6];
    const float* W_rel     = (const float*)d_in[7];
    const float* b_rel     = (const float*)d_in[8];
    const float* attn_src  = (const float*)d_in[9];
    const float* attn_dst  = (const float*)d_in[10];
    const float* attn_edge = (const float*)d_in[11];
    const float* W_edge    = (const float*)d_in[12];
    const float* b_edge    = (const float*)d_in[13];
    const int* src_idx     = (const int*)d_in[14];
    const int* dst_idx     = (const int*)d_in[15];
    const int* hn          = (const int*)d_in[16];
    const int* he          = (const int*)d_in[17];
    float* out = (float*)d_out;

    const int N    = in_sizes[0] / 64;
    const int EREL = in_sizes[6] / 32;
    const int E    = in_sizes[14];

    // Carve workspace
    char* ws = (char*)d_ws;
    auto alloc = [&](size_t bytes) {
        void* p = (void*)ws;
        ws += (bytes + 255) & ~(size_t)255;
        return p;
    };
    float* hp       = (float*)alloc((size_t)N * 64 * 4);
    float* mid_f    = (float*)alloc((size_t)N * 64 * 4);
    float* rel_f    = (float*)alloc((size_t)EREL * 64 * 4);
    float* e_src    = (float*)alloc((size_t)N * 2 * 4);
    float* e_dst    = (float*)alloc((size_t)N * 2 * 4);
    float* em       = (float*)alloc((size_t)N * 2 * 4);
    float* er       = (float*)alloc((size_t)EREL * 2 * 4);
    float* e_edge   = (float*)alloc((size_t)E * 2 * 4);
    int* deg        = (int*)alloc((size_t)N * 4);
    int* row_ptr    = (int*)alloc((size_t)(N + 1) * 4);
    int* cursor     = (int*)alloc((size_t)N * 4);
    int* edge_ids   = (int*)alloc((size_t)E * 4);

    hipMemsetAsync(deg, 0, (size_t)N * 4, stream);

    proj_attn_kernel<<<(N + 3) / 4, 256, 0, stream>>>(
        h, W_t, b_t, attn_src, attn_dst, 0, N, 64, hp, e_src, e_dst);
    proj_attn_kernel<<<(N + 3) / 4, 256, 0, stream>>>(
        nfeat_mid, W_mid, b_mid, attn_edge, nullptr, 1, N, 64, mid_f, em, nullptr);
    proj_attn_kernel<<<(EREL + 3) / 4, 256, 0, stream>>>(
        efeat_rel, W_rel, b_rel, attn_edge, nullptr, 2, EREL, 32, rel_f, er, nullptr);

    edge_logits_kernel<<<(E + 255) / 256, 256, 0, stream>>>(
        src_idx, dst_idx, hn, he, (const float2*)e_src, (const float2*)e_dst,
        (const float2*)em, (const float2*)er, (float2*)e_edge, deg, E);

    scan_kernel<<<1, 1024, 0, stream>>>(deg, row_ptr, cursor, N);

    scatter_kernel<<<(E + 255) / 256, 256, 0, stream>>>(
        dst_idx, cursor, edge_ids, E);

    aggregate_kernel<<<(N + 3) / 4, 256, 0, stream>>>(
        row_ptr, edge_ids, src_idx, hn, he, (const float2*)e_edge, hp, mid_f, rel_f,
        W_edge, b_edge, out, N);
}

// Round 3
// 461.456 us; speedup vs baseline: 1.5690x; 1.5690x over previous
//
#include <hip/hip_runtime.h>

typedef unsigned int uint;

__device__ __forceinline__ float bf16_lo(uint v) { return __uint_as_float(v << 16); }
__device__ __forceinline__ float bf16_hi(uint v) { return __uint_as_float(v & 0xffff0000u); }
__device__ __forceinline__ unsigned short f2bf(float f) {
    uint u = __float_as_uint(f);
    return (unsigned short)((u + 0x7fffu + ((u >> 16) & 1u)) >> 16);  // RNE
}
__device__ __forceinline__ float bf16u(unsigned short s) {
    return __uint_as_float(((uint)s) << 16);
}

// ---------------------------------------------------------------------------
// Tiled projection: out[row][c] = X[row,:K] @ W[:K,c] + b[c], plus per-head
// attention sums  outA[row] = { sum_c av[c]*relu(out), per head }.
// 64 rows/block, 256 threads: thread t -> row r=t>>2, colgroup cg=t&3,
// cols c = 16j + 4cg + q  (j,q in 0..3)  [interleaved to kill W bank conflicts]
// mode: avec index transform (0: attn_src/dst flat, 1: attn_edge mid half,
//       2: attn_edge rel half)
// ---------------------------------------------------------------------------
template<int K>
__global__ __launch_bounds__(256) void proj_kernel(
    const float* __restrict__ X, const float* __restrict__ W,
    const float* __restrict__ bias, const float* __restrict__ avec0,
    const float* __restrict__ avec1, int mode, int nrows,
    float* __restrict__ outF32, unsigned short* __restrict__ outF16,
    float2* __restrict__ outA0, float2* __restrict__ outA1)
{
    constexpr int XP = K + 4;          // padded row stride (floats), 16B-friendly
    __shared__ float Xsh[64 * XP];
    __shared__ float Wsh[K * 64];
    __shared__ float av0sh[64], av1sh[64], bsh[64];

    int t = threadIdx.x;

    // stage W as float4
    const float4* W4 = (const float4*)W;
    float4* Wsh4 = (float4*)Wsh;
    for (int i = t; i < K * 16; i += 256) Wsh4[i] = W4[i];

    // stage attention vectors + bias
    if (t < 64) {
        int head = t >> 5, d = t & 31;
        int aidx = (mode == 0) ? t : (mode == 1 ? head * 64 + d : head * 64 + 32 + d);
        av0sh[t] = avec0 ? avec0[aidx] : 0.f;
        av1sh[t] = avec1 ? avec1[aidx] : 0.f;
        bsh[t] = bias[t];
    }

    // stage X tile (64 rows), float4, row-clamped for the tail block
    int base = blockIdx.x * 64;
    const float4* X4 = (const float4*)X;
    for (int i = t; i < 64 * (K / 4); i += 256) {
        int row = i / (K / 4), c4 = i % (K / 4);
        int gr = base + row; if (gr >= nrows) gr = nrows - 1;
        float4 v = X4[(size_t)gr * (K / 4) + c4];
        *(float4*)&Xsh[row * XP + c4 * 4] = v;
    }
    __syncthreads();

    int r = t >> 2, cg = t & 3;
    float acc[4][4];
#pragma unroll
    for (int j = 0; j < 4; ++j)
#pragma unroll
        for (int q = 0; q < 4; ++q) acc[j][q] = 0.f;

    const float* xrow = &Xsh[r * XP];
#pragma unroll 8
    for (int k = 0; k < K; ++k) {
        float xk = xrow[k];
#pragma unroll
        for (int j = 0; j < 4; ++j) {
            float4 w = Wsh4[k * 16 + 4 * j + cg];
            acc[j][0] += xk * w.x;
            acc[j][1] += xk * w.y;
            acc[j][2] += xk * w.z;
            acc[j][3] += xk * w.w;
        }
    }

    // epilogue: bias, relu-attn sums, stores
    int row = base + r;
    float v[4][4];
    float s00 = 0.f, s01 = 0.f, s10 = 0.f, s11 = 0.f;
#pragma unroll
    for (int j = 0; j < 4; ++j)
#pragma unroll
        for (int q = 0; q < 4; ++q) {
            int c = 16 * j + 4 * cg + q;
            float val = acc[j][q] + bsh[c];
            v[j][q] = val;
            float rl = fmaxf(val, 0.f);
            float a0 = av0sh[c] * rl, a1 = av1sh[c] * rl;
            if (j < 2) { s00 += a0; s10 += a1; }   // cols < 32 (head 0)
            else       { s01 += a0; s11 += a1; }   // cols >= 32 (head 1)
        }
    // reduce across the 4 colgroup lanes (bits 0,1 of lane)
    s00 += __shfl_xor(s00, 1, 64); s00 += __shfl_xor(s00, 2, 64);
    s01 += __shfl_xor(s01, 1, 64); s01 += __shfl_xor(s01, 2, 64);
    s10 += __shfl_xor(s10, 1, 64); s10 += __shfl_xor(s10, 2, 64);
    s11 += __shfl_xor(s11, 1, 64); s11 += __shfl_xor(s11, 2, 64);

    if (row < nrows) {
        if (outF32) {
#pragma unroll
            for (int j = 0; j < 4; ++j) {
                float4 sv = make_float4(v[j][0], v[j][1], v[j][2], v[j][3]);
                *(float4*)&outF32[(size_t)row * 64 + 16 * j + 4 * cg] = sv;
            }
        }
#pragma unroll
        for (int j = 0; j < 4; ++j) {
            uint u0 = (uint)f2bf(v[j][0]) | ((uint)f2bf(v[j][1]) << 16);
            uint u1 = (uint)f2bf(v[j][2]) | ((uint)f2bf(v[j][3]) << 16);
            uint2 uv = make_uint2(u0, u1);
            *(uint2*)&outF16[(size_t)row * 64 + 16 * j + 4 * cg] = uv;
        }
        if (cg == 0 && outA0) outA0[row] = make_float2(s00, s01);
        if (cg == 1 && outA1) outA1[row] = make_float2(s10, s11);
    }
}

// ---------------------------------------------------------------------------
__global__ __launch_bounds__(256) void deg_kernel(
    const int* __restrict__ dst, int* __restrict__ deg, int E)
{
    int i = blockIdx.x * blockDim.x + threadIdx.x;
    if (i >= E) return;
    atomicAdd(&deg[dst[i]], 1);
}

// ---------------------------------------------------------------------------
__global__ __launch_bounds__(1024) void scan_kernel(
    const int* __restrict__ deg, int* __restrict__ row_ptr,
    int* __restrict__ cursor, int N)
{
    __shared__ int part[1024];
    int t = threadIdx.x;
    int chunk = (N + 1023) / 1024;
    int lo = t * chunk, hi = min(lo + chunk, N);
    int s = 0;
    for (int i = lo; i < hi; ++i) s += deg[i];
    part[t] = s;
    __syncthreads();
    for (int off = 1; off < 1024; off <<= 1) {
        int vv = 0;
        if (t >= off) vv = part[t - off];
        __syncthreads();
        if (t >= off) part[t] += vv;
        __syncthreads();
    }
    int ex = (t == 0) ? 0 : part[t - 1];
    for (int i = lo; i < hi; ++i) {
        row_ptr[i] = ex;
        cursor[i] = ex;
        ex += deg[i];
    }
    if (t == 1023) row_ptr[N] = part[1023];
}

// ---------------------------------------------------------------------------
// Fused edge-logit + CSR scatter: compute per-edge logits from the 4 small
// per-entity tables and write (meta, e2) into CSR slots.
// ---------------------------------------------------------------------------
__global__ __launch_bounds__(256) void scatter_kernel(
    const int* __restrict__ src, const int* __restrict__ dst,
    const int* __restrict__ hn, const int* __restrict__ he,
    const float2* __restrict__ es, const float2* __restrict__ ed,
    const float2* __restrict__ em, const float2* __restrict__ er,
    int* __restrict__ cursor, int4* __restrict__ meta,
    float2* __restrict__ e2, int E)
{
    int i = blockIdx.x * blockDim.x + threadIdx.x;
    if (i >= E) return;
    int s = src[i], d = dst[i], a = hn[i], b = he[i];
    float2 v1 = es[s], v2 = ed[d], v3 = em[a], v4 = er[b];
    float2 ev = make_float2(v1.x + v2.x + v3.x + v4.x, v1.y + v2.y + v3.y + v4.y);
    int pos = atomicAdd(&cursor[d], 1);
    meta[pos] = make_int4(s, a, b, 0);
    e2[pos] = ev;
}

// ---------------------------------------------------------------------------
// Per-node aggregation. One wave per node; lane = head*32 + dj.
// Pass 1: softmax max over CSR-sequential e2. Pass 2: exp-sum + weighted
// feature aggregation with bf16 gathers (hp row: 1 ushort/lane; mid+rel rows:
// 1 dword/lane with per-lane table select). Then fc_edge, residual, relu,
// L2-normalize.
// ---------------------------------------------------------------------------
__global__ __launch_bounds__(256) void aggregate_kernel(
    const int* __restrict__ row_ptr, const int4* __restrict__ meta,
    const float2* __restrict__ e2, const float* __restrict__ hp32,
    const unsigned short* __restrict__ hp16,
    const unsigned short* __restrict__ mid16,
    const unsigned short* __restrict__ rel16,
    const float* __restrict__ We, const float* __restrict__ be,
    float* __restrict__ out, int N)
{
    __shared__ float WeSh[64 * 32];
    __shared__ float ft2sh[4][128];
    int t = threadIdx.x;
    for (int i = t; i < 64 * 32; i += 256) WeSh[i] = We[i];
    __syncthreads();

    int wave = t >> 6, lane = t & 63;
    int head = lane >> 5, dj = lane & 31;
    int n = blockIdx.x * 4 + wave;
    bool valid = n < N;
    int nn = valid ? n : 0;

    int start = row_ptr[nn], end = row_ptr[nn + 1];

    // pass 1: per-head max (CSR-sequential, lanes stride)
    float m0 = -1e30f, m1 = -1e30f;
    for (int i = start + lane; i < end; i += 64) {
        float2 ev = e2[i];
        m0 = fmaxf(m0, ev.x);
        m1 = fmaxf(m1, ev.y);
    }
    for (int m = 32; m >= 1; m >>= 1) {
        m0 = fmaxf(m0, __shfl_xor(m0, m, 64));
        m1 = fmaxf(m1, __shfl_xor(m1, m, 64));
    }

    // pass 2
    bool isrel = lane >= 32;
    int l31 = lane & 31;
    bool h1w = ((lane >> 4) & 1) != 0;   // lanes 16-31, 48-63 carry head-1 channels
    float rstc = 0.f, fx = 0.f, fy = 0.f, den0 = 0.f, den1 = 0.f;
#pragma unroll 2
    for (int i = start; i < end; ++i) {
        int4 mv = meta[i];
        float2 ev = e2[i];
        float a0 = __expf(ev.x - m0);
        float a1 = __expf(ev.y - m1);
        den0 += a0; den1 += a1;
        // hp gather (bf16 row, 1 ushort per lane)
        unsigned short hu = hp16[(size_t)mv.x * 64 + lane];
        rstc += bf16u(hu) * (head ? a1 : a0);
        // mid/rel combined gather: one dword per lane (2 bf16 channels)
        const unsigned short* bp = isrel ? (rel16 + ((size_t)mv.z << 6))
                                         : (mid16 + ((size_t)mv.y << 6));
        uint pv = ((const uint*)bp)[l31];
        float w = h1w ? a1 : a0;
        fx += bf16_lo(pv) * w;
        fy += bf16_hi(pv) * w;
    }
    float inv0 = den0 > 0.f ? 1.f / den0 : 0.f;
    float inv1 = den1 > 0.f ? 1.f / den1 : 0.f;
    rstc *= head ? inv1 : inv0;
    float invf = h1w ? inv1 : inv0;

    // ft2 slot mapping (concat layout [head][64])
    int slotbase;
    if (lane < 16)      slotbase = 2 * lane;            // h0 mid: ch 0..31
    else if (lane < 32) slotbase = 2 * lane + 32;       // h1 mid: 64 + (ch-32)
    else if (lane < 48) slotbase = 2 * lane - 32;       // h0 rel: 32 + ch
    else                slotbase = 2 * lane;            // h1 rel: 64 + ch
    ft2sh[wave][slotbase]     = fx * invf;
    ft2sh[wave][slotbase + 1] = fy * invf;
    __syncthreads();

    // fc_edge
    float fc = be[dj];
#pragma unroll 8
    for (int dd = 0; dd < 64; ++dd)
        fc += ft2sh[wave][head * 64 + dd] * WeSh[dd * 32 + dj];

    float val = rstc + fc + hp32[(size_t)nn * 64 + lane];
    val = fmaxf(val, 0.f);

    float ss = val * val;
    for (int m = 32; m >= 1; m >>= 1) ss += __shfl_xor(ss, m, 64);
    float invn = 1.f / fmaxf(sqrtf(ss), 1e-12f);
    if (valid) out[(size_t)nn * 64 + lane] = val * invn;
}

// ---------------------------------------------------------------------------
extern "C" void kernel_launch(void* const* d_in, const int* in_sizes, int n_in,
                              void* d_out, int out_size, void* d_ws, size_t ws_size,
                              hipStream_t stream)
{
    const float* h         = (const float*)d_in[0];
    const float* W_t       = (const float*)d_in[1];
    const float* b_t       = (const float*)d_in[2];
    const float* nfeat_mid = (const float*)d_in[3];
    const float* W_mid     = (const float*)d_in[4];
    const float* b_mid     = (const float*)d_in[5];
    const float* efeat_rel = (const float*)d_in[6];
    const float* W_rel     = (const float*)d_in[7];
    const float* b_rel     = (const float*)d_in[8];
    const float* attn_src  = (const float*)d_in[9];
    const float* attn_dst  = (const float*)d_in[10];
    const float* attn_edge = (const float*)d_in[11];
    const float* W_edge    = (const float*)d_in[12];
    const float* b_edge    = (const float*)d_in[13];
    const int* src_idx     = (const int*)d_in[14];
    const int* dst_idx     = (const int*)d_in[15];
    const int* hn          = (const int*)d_in[16];
    const int* he          = (const int*)d_in[17];
    float* out = (float*)d_out;

    const int N    = in_sizes[0] / 64;
    const int EREL = in_sizes[6] / 32;
    const int E    = in_sizes[14];

    char* ws = (char*)d_ws;
    auto alloc = [&](size_t bytes) {
        void* p = (void*)ws;
        ws += (bytes + 255) & ~(size_t)255;
        return p;
    };
    float* hp32           = (float*)alloc((size_t)N * 64 * 4);
    unsigned short* hp16  = (unsigned short*)alloc((size_t)N * 64 * 2);
    unsigned short* mid16 = (unsigned short*)alloc((size_t)N * 64 * 2);
    unsigned short* rel16 = (unsigned short*)alloc((size_t)EREL * 64 * 2);
    float2* e_src  = (float2*)alloc((size_t)N * 8);
    float2* e_dst  = (float2*)alloc((size_t)N * 8);
    float2* em     = (float2*)alloc((size_t)N * 8);
    float2* er     = (float2*)alloc((size_t)EREL * 8);
    int* deg       = (int*)alloc((size_t)N * 4);
    int* row_ptr   = (int*)alloc((size_t)(N + 1) * 4);
    int* cursor    = (int*)alloc((size_t)N * 4);
    int4* meta     = (int4*)alloc((size_t)E * 16);
    float2* e2     = (float2*)alloc((size_t)E * 8);

    hipMemsetAsync(deg, 0, (size_t)N * 4, stream);

    proj_kernel<64><<<(N + 63) / 64, 256, 0, stream>>>(
        h, W_t, b_t, attn_src, attn_dst, 0, N, hp32, hp16, e_src, e_dst);
    proj_kernel<64><<<(N + 63) / 64, 256, 0, stream>>>(
        nfeat_mid, W_mid, b_mid, attn_edge, nullptr, 1, N, nullptr, mid16, em, nullptr);
    proj_kernel<32><<<(EREL + 63) / 64, 256, 0, stream>>>(
        efeat_rel, W_rel, b_rel, attn_edge, nullptr, 2, EREL, nullptr, rel16, er, nullptr);

    deg_kernel<<<(E + 255) / 256, 256, 0, stream>>>(dst_idx, deg, E);

    scan_kernel<<<1, 1024, 0, stream>>>(deg, row_ptr, cursor, N);

    scatter_kernel<<<(E + 255) / 256, 256, 0, stream>>>(
        src_idx, dst_idx, hn, he, e_src, e_dst, em, er, cursor, meta, e2, E);

    aggregate_kernel<<<(N + 3) / 4, 256, 0, stream>>>(
        row_ptr, meta, e2, hp32, hp16, mid16, rel16, W_edge, b_edge, out, N);
}

// Round 4
// 356.074 us; speedup vs baseline: 2.0334x; 1.2960x over previous
//
#include <hip/hip_runtime.h>

typedef unsigned int uint;

__device__ __forceinline__ float bf16_lo(uint v) { return __uint_as_float(v << 16); }
__device__ __forceinline__ float bf16_hi(uint v) { return __uint_as_float(v & 0xffff0000u); }
__device__ __forceinline__ unsigned short f2bf(float f) {
    uint u = __float_as_uint(f);
    return (unsigned short)((u + 0x7fffu + ((u >> 16) & 1u)) >> 16);  // RNE
}
__device__ __forceinline__ float bf16u(unsigned short s) {
    return __uint_as_float(((uint)s) << 16);
}

// ---------------------------------------------------------------------------
// Tiled projection: out[row][c] = X[row,:K] @ W[:K,c] + b[c], plus per-head
// attention sums  outA[row] = { sum_c av[c]*relu(out), per head }.
// 64 rows/block, 256 threads: thread t -> row r=t>>2, colgroup cg=t&3,
// cols c = 16j + 4cg + q  (j,q in 0..3)
// ---------------------------------------------------------------------------
template<int K>
__global__ __launch_bounds__(256) void proj_kernel(
    const float* __restrict__ X, const float* __restrict__ W,
    const float* __restrict__ bias, const float* __restrict__ avec0,
    const float* __restrict__ avec1, int mode, int nrows,
    float* __restrict__ outF32, unsigned short* __restrict__ outF16,
    float2* __restrict__ outA0, float2* __restrict__ outA1)
{
    constexpr int XP = K + 4;
    __shared__ float Xsh[64 * XP];
    __shared__ float Wsh[K * 64];
    __shared__ float av0sh[64], av1sh[64], bsh[64];

    int t = threadIdx.x;

    const float4* W4 = (const float4*)W;
    float4* Wsh4 = (float4*)Wsh;
    for (int i = t; i < K * 16; i += 256) Wsh4[i] = W4[i];

    if (t < 64) {
        int head = t >> 5, d = t & 31;
        int aidx = (mode == 0) ? t : (mode == 1 ? head * 64 + d : head * 64 + 32 + d);
        av0sh[t] = avec0 ? avec0[aidx] : 0.f;
        av1sh[t] = avec1 ? avec1[aidx] : 0.f;
        bsh[t] = bias[t];
    }

    int base = blockIdx.x * 64;
    const float4* X4 = (const float4*)X;
    for (int i = t; i < 64 * (K / 4); i += 256) {
        int row = i / (K / 4), c4 = i % (K / 4);
        int gr = base + row; if (gr >= nrows) gr = nrows - 1;
        float4 v = X4[(size_t)gr * (K / 4) + c4];
        *(float4*)&Xsh[row * XP + c4 * 4] = v;
    }
    __syncthreads();

    int r = t >> 2, cg = t & 3;
    float acc[4][4];
#pragma unroll
    for (int j = 0; j < 4; ++j)
#pragma unroll
        for (int q = 0; q < 4; ++q) acc[j][q] = 0.f;

    const float* xrow = &Xsh[r * XP];
#pragma unroll 8
    for (int k = 0; k < K; ++k) {
        float xk = xrow[k];
#pragma unroll
        for (int j = 0; j < 4; ++j) {
            float4 w = Wsh4[k * 16 + 4 * j + cg];
            acc[j][0] += xk * w.x;
            acc[j][1] += xk * w.y;
            acc[j][2] += xk * w.z;
            acc[j][3] += xk * w.w;
        }
    }

    int row = base + r;
    float v[4][4];
    float s00 = 0.f, s01 = 0.f, s10 = 0.f, s11 = 0.f;
#pragma unroll
    for (int j = 0; j < 4; ++j)
#pragma unroll
        for (int q = 0; q < 4; ++q) {
            int c = 16 * j + 4 * cg + q;
            float val = acc[j][q] + bsh[c];
            v[j][q] = val;
            float rl = fmaxf(val, 0.f);
            float a0 = av0sh[c] * rl, a1 = av1sh[c] * rl;
            if (j < 2) { s00 += a0; s10 += a1; }
            else       { s01 += a0; s11 += a1; }
        }
    s00 += __shfl_xor(s00, 1, 64); s00 += __shfl_xor(s00, 2, 64);
    s01 += __shfl_xor(s01, 1, 64); s01 += __shfl_xor(s01, 2, 64);
    s10 += __shfl_xor(s10, 1, 64); s10 += __shfl_xor(s10, 2, 64);
    s11 += __shfl_xor(s11, 1, 64); s11 += __shfl_xor(s11, 2, 64);

    if (row < nrows) {
        if (outF32) {
#pragma unroll
            for (int j = 0; j < 4; ++j) {
                float4 sv = make_float4(v[j][0], v[j][1], v[j][2], v[j][3]);
                *(float4*)&outF32[(size_t)row * 64 + 16 * j + 4 * cg] = sv;
            }
        }
#pragma unroll
        for (int j = 0; j < 4; ++j) {
            uint u0 = (uint)f2bf(v[j][0]) | ((uint)f2bf(v[j][1]) << 16);
            uint u1 = (uint)f2bf(v[j][2]) | ((uint)f2bf(v[j][3]) << 16);
            uint2 uv = make_uint2(u0, u1);
            *(uint2*)&outF16[(size_t)row * 64 + 16 * j + 4 * cg] = uv;
        }
        if (cg == 0 && outA0) outA0[row] = make_float2(s00, s01);
        if (cg == 1 && outA1) outA1[row] = make_float2(s10, s11);
    }
}

// ---------------------------------------------------------------------------
__global__ __launch_bounds__(256) void deg_kernel(
    const int* __restrict__ dst, int* __restrict__ deg, int E)
{
    int i = blockIdx.x * blockDim.x + threadIdx.x;
    if (i >= E) return;
    atomicAdd(&deg[dst[i]], 1);
}

// ---------------------------------------------------------------------------
// Hierarchical scan, stage A: per-block (1024 elems) sums
// ---------------------------------------------------------------------------
__global__ __launch_bounds__(256) void scanA_kernel(
    const int* __restrict__ deg, int* __restrict__ blkSums, int N)
{
    __shared__ int red[256];
    int t = threadIdx.x;
    int base = blockIdx.x * 1024 + t * 4;
    int s = 0;
    if (base + 3 < N) {
        int4 v = *(const int4*)&deg[base];
        s = v.x + v.y + v.z + v.w;
    } else {
        for (int i = 0; i < 4; ++i) if (base + i < N) s += deg[base + i];
    }
    red[t] = s;
    __syncthreads();
    for (int off = 128; off >= 1; off >>= 1) {
        if (t < off) red[t] += red[t + off];
        __syncthreads();
    }
    if (t == 0) blkSums[blockIdx.x] = red[0];
}

// ---------------------------------------------------------------------------
// Hierarchical scan, stage C: block offset (wave-parallel over <=64 block
// sums) + local Hillis-Steele scan + write row_ptr / cursor.
// ---------------------------------------------------------------------------
__global__ __launch_bounds__(256) void scanC_kernel(
    const int* __restrict__ deg, const int* __restrict__ blkSums,
    int* __restrict__ row_ptr, int* __restrict__ cursor, int N, int nblk)
{
    __shared__ int sh[256];
    __shared__ int blkOffSh;
    int t = threadIdx.x;
    int blk = blockIdx.x;
    int base = blk * 1024 + t * 4;

    if (t < 64) {
        int s = (t < blk && t < nblk) ? blkSums[t] : 0;
        for (int m = 32; m >= 1; m >>= 1) s += __shfl_xor(s, m, 64);
        if (t == 0) blkOffSh = s;
    }

    int4 v = make_int4(0, 0, 0, 0);
    if (base + 3 < N) v = *(const int4*)&deg[base];
    else {
        if (base < N)     v.x = deg[base];
        if (base + 1 < N) v.y = deg[base + 1];
        if (base + 2 < N) v.z = deg[base + 2];
    }
    int ts = v.x + v.y + v.z + v.w;
    sh[t] = ts;
    __syncthreads();
    for (int off = 1; off < 256; off <<= 1) {
        int val = (t >= off) ? sh[t - off] : 0;
        __syncthreads();
        sh[t] += val;
        __syncthreads();
    }
    int blkOff = blkOffSh;
    int ex = blkOff + ((t == 0) ? 0 : sh[t - 1]);
    int p0 = ex, p1 = ex + v.x, p2 = p1 + v.y, p3 = p2 + v.z;
    if (base < N)     { row_ptr[base]     = p0; cursor[base]     = p0; }
    if (base + 1 < N) { row_ptr[base + 1] = p1; cursor[base + 1] = p1; }
    if (base + 2 < N) { row_ptr[base + 2] = p2; cursor[base + 2] = p2; }
    if (base + 3 < N) { row_ptr[base + 3] = p3; cursor[base + 3] = p3; }
    if (blk == nblk - 1 && t == 255) row_ptr[N] = blkOff + sh[255];
}

// ---------------------------------------------------------------------------
// Fused edge-logit + CSR scatter
// ---------------------------------------------------------------------------
__global__ __launch_bounds__(256) void scatter_kernel(
    const int* __restrict__ src, const int* __restrict__ dst,
    const int* __restrict__ hn, const int* __restrict__ he,
    const float2* __restrict__ es, const float2* __restrict__ ed,
    const float2* __restrict__ em, const float2* __restrict__ er,
    int* __restrict__ cursor, int4* __restrict__ meta,
    float2* __restrict__ e2, int E)
{
    int i = blockIdx.x * blockDim.x + threadIdx.x;
    if (i >= E) return;
    int s = src[i], d = dst[i], a = hn[i], b = he[i];
    float2 v1 = es[s], v2 = ed[d], v3 = em[a], v4 = er[b];
    float2 ev = make_float2(v1.x + v2.x + v3.x + v4.x, v1.y + v2.y + v3.y + v4.y);
    int pos = atomicAdd(&cursor[d], 1);
    meta[pos] = make_int4(s, a, b, 0);
    e2[pos] = ev;
}

// ---------------------------------------------------------------------------
// Per-node aggregation. One wave per node; lane = head*32 + dj.
// ---------------------------------------------------------------------------
__global__ __launch_bounds__(256) void aggregate_kernel(
    const int* __restrict__ row_ptr, const int4* __restrict__ meta,
    const float2* __restrict__ e2, const float* __restrict__ hp32,
    const unsigned short* __restrict__ hp16,
    const unsigned short* __restrict__ mid16,
    const unsigned short* __restrict__ rel16,
    const float* __restrict__ We, const float* __restrict__ be,
    float* __restrict__ out, int N)
{
    __shared__ float WeSh[64 * 32];
    __shared__ float ft2sh[4][128];
    int t = threadIdx.x;
    for (int i = t; i < 64 * 32; i += 256) WeSh[i] = We[i];
    __syncthreads();

    int wave = t >> 6, lane = t & 63;
    int head = lane >> 5, dj = lane & 31;
    int n = blockIdx.x * 4 + wave;
    bool valid = n < N;
    int nn = valid ? n : 0;

    int start = row_ptr[nn], end = row_ptr[nn + 1];

    // pass 1: per-head max (CSR-sequential, lanes stride)
    float m0 = -1e30f, m1 = -1e30f;
    for (int i = start + lane; i < end; i += 64) {
        float2 ev = e2[i];
        m0 = fmaxf(m0, ev.x);
        m1 = fmaxf(m1, ev.y);
    }
    for (int m = 32; m >= 1; m >>= 1) {
        m0 = fmaxf(m0, __shfl_xor(m0, m, 64));
        m1 = fmaxf(m1, __shfl_xor(m1, m, 64));
    }

    // pass 2
    bool isrel = lane >= 32;
    int l31 = lane & 31;
    bool h1w = ((lane >> 4) & 1) != 0;
    float rstc = 0.f, fx = 0.f, fy = 0.f, den0 = 0.f, den1 = 0.f;
#pragma unroll 2
    for (int i = start; i < end; ++i) {
        int4 mv = meta[i];
        float2 ev = e2[i];
        float a0 = __expf(ev.x - m0);
        float a1 = __expf(ev.y - m1);
        den0 += a0; den1 += a1;
        unsigned short hu = hp16[(size_t)mv.x * 64 + lane];
        rstc += bf16u(hu) * (head ? a1 : a0);
        const unsigned short* bp = isrel ? (rel16 + ((size_t)mv.z << 6))
                                         : (mid16 + ((size_t)mv.y << 6));
        uint pv = ((const uint*)bp)[l31];
        float w = h1w ? a1 : a0;
        fx += bf16_lo(pv) * w;
        fy += bf16_hi(pv) * w;
    }
    float inv0 = den0 > 0.f ? 1.f / den0 : 0.f;
    float inv1 = den1 > 0.f ? 1.f / den1 : 0.f;
    rstc *= head ? inv1 : inv0;
    float invf = h1w ? inv1 : inv0;

    int slotbase;
    if (lane < 16)      slotbase = 2 * lane;
    else if (lane < 32) slotbase = 2 * lane + 32;
    else if (lane < 48) slotbase = 2 * lane - 32;
    else                slotbase = 2 * lane;
    ft2sh[wave][slotbase]     = fx * invf;
    ft2sh[wave][slotbase + 1] = fy * invf;

    // wave-local LDS fence (ft2sh region is per-wave; avoid coupling the 4
    // waves of this block through a full __syncthreads straggler barrier)
    __builtin_amdgcn_sched_barrier(0);
    asm volatile("s_waitcnt lgkmcnt(0)" ::: "memory");
    __builtin_amdgcn_sched_barrier(0);

    float fc = be[dj];
#pragma unroll 8
    for (int dd = 0; dd < 64; ++dd)
        fc += ft2sh[wave][head * 64 + dd] * WeSh[dd * 32 + dj];

    float val = rstc + fc + hp32[(size_t)nn * 64 + lane];
    val = fmaxf(val, 0.f);

    float ss = val * val;
    for (int m = 32; m >= 1; m >>= 1) ss += __shfl_xor(ss, m, 64);
    float invn = 1.f / fmaxf(sqrtf(ss), 1e-12f);
    if (valid) out[(size_t)nn * 64 + lane] = val * invn;
}

// ---------------------------------------------------------------------------
extern "C" void kernel_launch(void* const* d_in, const int* in_sizes, int n_in,
                              void* d_out, int out_size, void* d_ws, size_t ws_size,
                              hipStream_t stream)
{
    const float* h         = (const float*)d_in[0];
    const float* W_t       = (const float*)d_in[1];
    const float* b_t       = (const float*)d_in[2];
    const float* nfeat_mid = (const float*)d_in[3];
    const float* W_mid     = (const float*)d_in[4];
    const float* b_mid     = (const float*)d_in[5];
    const float* efeat_rel = (const float*)d_in[6];
    const float* W_rel     = (const float*)d_in[7];
    const float* b_rel     = (const float*)d_in[8];
    const float* attn_src  = (const float*)d_in[9];
    const float* attn_dst  = (const float*)d_in[10];
    const float* attn_edge = (const float*)d_in[11];
    const float* W_edge    = (const float*)d_in[12];
    const float* b_edge    = (const float*)d_in[13];
    const int* src_idx     = (const int*)d_in[14];
    const int* dst_idx     = (const int*)d_in[15];
    const int* hn          = (const int*)d_in[16];
    const int* he          = (const int*)d_in[17];
    float* out = (float*)d_out;

    const int N    = in_sizes[0] / 64;
    const int EREL = in_sizes[6] / 32;
    const int E    = in_sizes[14];

    char* ws = (char*)d_ws;
    auto alloc = [&](size_t bytes) {
        void* p = (void*)ws;
        ws += (bytes + 255) & ~(size_t)255;
        return p;
    };
    float* hp32           = (float*)alloc((size_t)N * 64 * 4);
    unsigned short* hp16  = (unsigned short*)alloc((size_t)N * 64 * 2);
    unsigned short* mid16 = (unsigned short*)alloc((size_t)N * 64 * 2);
    unsigned short* rel16 = (unsigned short*)alloc((size_t)EREL * 64 * 2);
    float2* e_src  = (float2*)alloc((size_t)N * 8);
    float2* e_dst  = (float2*)alloc((size_t)N * 8);
    float2* em     = (float2*)alloc((size_t)N * 8);
    float2* er     = (float2*)alloc((size_t)EREL * 8);
    int* deg       = (int*)alloc((size_t)N * 4);
    int* row_ptr   = (int*)alloc((size_t)(N + 1) * 4);
    int* cursor    = (int*)alloc((size_t)N * 4);
    int* blkSums   = (int*)alloc((size_t)64 * 4);
    int4* meta     = (int4*)alloc((size_t)E * 16);
    float2* e2     = (float2*)alloc((size_t)E * 8);

    hipMemsetAsync(deg, 0, (size_t)N * 4, stream);

    proj_kernel<64><<<(N + 63) / 64, 256, 0, stream>>>(
        h, W_t, b_t, attn_src, attn_dst, 0, N, hp32, hp16, e_src, e_dst);
    proj_kernel<64><<<(N + 63) / 64, 256, 0, stream>>>(
        nfeat_mid, W_mid, b_mid, attn_edge, nullptr, 1, N, nullptr, mid16, em, nullptr);
    proj_kernel<32><<<(EREL + 63) / 64, 256, 0, stream>>>(
        efeat_rel, W_rel, b_rel, attn_edge, nullptr, 2, EREL, nullptr, rel16, er, nullptr);

    deg_kernel<<<(E + 255) / 256, 256, 0, stream>>>(dst_idx, deg, E);

    int nblk = (N + 1023) / 1024;   // 49 for N=50000 (fits the 64-wide offset reduce)
    scanA_kernel<<<nblk, 256, 0, stream>>>(deg, blkSums, N);
    scanC_kernel<<<nblk, 256, 0, stream>>>(deg, blkSums, row_ptr, cursor, N, nblk);

    scatter_kernel<<<(E + 255) / 256, 256, 0, stream>>>(
        src_idx, dst_idx, hn, he, e_src, e_dst, em, er, cursor, meta, e2, E);

    aggregate_kernel<<<(N + 3) / 4, 256, 0, stream>>>(
        row_ptr, meta, e2, hp32, hp16, mid16, rel16, W_edge, b_edge, out, N);
}